// Round 14
// baseline (698.636 us; speedup 1.0000x reference)
//
#include <hip/hip_runtime.h>
#include <hip/hip_fp16.h>

#define DD 128
#define HH 6

typedef _Float16 f16;
typedef _Float16 f16x2 __attribute__((ext_vector_type(2)));
typedef _Float16 f16x8 __attribute__((ext_vector_type(8)));
typedef float f32x4 __attribute__((ext_vector_type(4)));

// ---------------- encoder: x = relu([pos,norm] @ w1.T + b1) -> fp16 ----------------
__global__ void enc_kernel(const float* __restrict__ pos, const float* __restrict__ nrm,
                           const float* __restrict__ w1, const float* __restrict__ b1,
                           f16* __restrict__ x, int n) {
  int i = blockIdx.x;
  int d = threadIdx.x;
  if (i >= n) return;
  float in[6];
  in[0] = pos[i*3+0]; in[1] = pos[i*3+1]; in[2] = pos[i*3+2];
  in[3] = nrm[i*3+0]; in[4] = nrm[i*3+1]; in[5] = nrm[i*3+2];
  const float* wr = w1 + d*6;
  float acc = b1[d];
  #pragma unroll
  for (int k = 0; k < 6; k++) acc = fmaf(in[k], wr[k], acc);
  x[(size_t)i*DD + d] = (f16)fmaxf(acc, 0.0f);
}

// ---------------- degree histogram ----------------
__global__ void hist_kernel(const int* __restrict__ dst, int e, int* __restrict__ cnt) {
  int i = blockIdx.x*blockDim.x + threadIdx.x;
  if (i < e) atomicAdd(&cnt[dst[i]], 1);
}

// ---------------- exclusive scan (3 kernels) ----------------
__global__ void scan_blk_kernel(const int* __restrict__ cnt, int* __restrict__ rowptr,
                                int* __restrict__ bsum, int n) {
  __shared__ int s[256];
  int tid = threadIdx.x;
  int i = blockIdx.x*256 + tid;
  int v = (i < n) ? cnt[i] : 0;
  s[tid] = v; __syncthreads();
  #pragma unroll
  for (int off = 1; off < 256; off <<= 1) {
    int t = (tid >= off) ? s[tid-off] : 0;
    __syncthreads();
    s[tid] += t;
    __syncthreads();
  }
  if (i < n) rowptr[i] = s[tid] - v;
  if (tid == 255) bsum[blockIdx.x] = s[255];
}

__global__ void scan_top_kernel(int* bsum, int nb) {
  __shared__ int s[256];
  int tid = threadIdx.x;
  int v = (tid < nb) ? bsum[tid] : 0;
  s[tid] = v; __syncthreads();
  #pragma unroll
  for (int off = 1; off < 256; off <<= 1) {
    int t = (tid >= off) ? s[tid-off] : 0;
    __syncthreads();
    s[tid] += t;
    __syncthreads();
  }
  if (tid < nb) bsum[tid] = s[tid] - v;
}

// rowptr finalize + invdeg fused
__global__ void scan_add_kernel(int* rowptr, const int* __restrict__ bsum,
                                const int* __restrict__ cnt, float* __restrict__ invdeg,
                                int n, int e) {
  int i = blockIdx.x*256 + threadIdx.x;
  if (i < n) {
    rowptr[i] += bsum[blockIdx.x];
    invdeg[i] = 1.0f / (float)max(cnt[i], 1);
  }
  if (i == 0) rowptr[n] = e;
}

// ---------------- CSR fill: sd_pair[p] = {src, dst}  (single 8B scatter/edge) ----------------
__global__ void fill_kernel(const int* __restrict__ src, const int* __restrict__ dst, int e,
                            const int* __restrict__ rowptr, int* __restrict__ fc,
                            int2* __restrict__ sd_pair) {
  int i = blockIdx.x*blockDim.x + threadIdx.x;
  if (i >= e) return;
  int dd = dst[i];
  int p = rowptr[dd] + atomicAdd(&fc[dd], 1);
  sd_pair[p] = make_int2(src[i], dd);
}

// ---------------- z = x @ u.T  [N,6]  (x fp16) ----------------
__global__ void z_kernel(const f16* __restrict__ x, const float* __restrict__ u,
                         float* __restrict__ z, int n) {
  int node = blockIdx.x*4 + (threadIdx.x >> 6);
  int l = threadIdx.x & 63;
  if (node >= n) return;
  f16x2 v = *(const f16x2*)&x[(size_t)node*DD + 2*l];
  float vx = (float)v[0], vy = (float)v[1];
  float p[HH];
  #pragma unroll
  for (int h = 0; h < HH; h++) {
    float2 uv = *(const float2*)&u[h*DD + 2*l];
    p[h] = vx*uv.x + vy*uv.y;
  }
  #pragma unroll
  for (int off = 32; off; off >>= 1) {
    #pragma unroll
    for (int h = 0; h < HH; h++) p[h] += __shfl_xor(p[h], off, 64);
  }
  if (l == 0) {
    #pragma unroll
    for (int h = 0; h < HH; h++) z[(size_t)node*HH + h] = p[h];
  }
}

// ---------------- per-slot softmax -> fp16 q sequential (deg-divide folded) ----------------
__global__ void q_kernel(const int2* __restrict__ sd_pair,
                         const float* __restrict__ z, const float* __restrict__ c,
                         const float* __restrict__ invdeg,
                         f16* __restrict__ qcsr, int e) {
  int i = blockIdx.x*blockDim.x + threadIdx.x;
  if (i >= e) return;
  int2 sd = sd_pair[i];
  int s = sd.x, dd = sd.y;
  float l[HH];
  float m = -1e30f;
  #pragma unroll
  for (int h = 0; h < HH; h++) {
    l[h] = z[(size_t)s*HH + h] - z[(size_t)dd*HH + h] + c[h];
    m = fmaxf(m, l[h]);
  }
  float sum = 0.f;
  #pragma unroll
  for (int h = 0; h < HH; h++) { l[h] = __expf(l[h] - m); sum += l[h]; }
  float r = invdeg[dd] / sum;
  size_t p = (size_t)i*HH;
  f16x2 o0 = {(f16)(l[0]*r), (f16)(l[1]*r)};
  f16x2 o1 = {(f16)(l[2]*r), (f16)(l[3]*r)};
  f16x2 o2 = {(f16)(l[4]*r), (f16)(l[5]*r)};
  *(f16x2*)&qcsr[p+0] = o0;
  *(f16x2*)&qcsr[p+2] = o1;
  *(f16x2*)&qcsr[p+4] = o2;
}

// ---------------- W concat+convert, all 4 layers: Wc[l][nr][h*128+d] = (f16)W_l[h][nr][d] ----------------
__global__ void wc4_kernel(const float* __restrict__ W0, const float* __restrict__ W1,
                           const float* __restrict__ W2, const float* __restrict__ W3,
                           f16* __restrict__ Wc) {
  int id = blockIdx.x*256 + threadIdx.x;
  if (id >= 4*HH*DD*DD) return;
  int l = id / (HH*DD*DD);
  int r = id - l*(HH*DD*DD);
  const float* W = (l == 0) ? W0 : (l == 1) ? W1 : (l == 2) ? W2 : W3;
  int h = r >> 14, rem = r & 16383, nr = rem >> 7, d = rem & 127;
  Wc[(size_t)l*(HH*DD*DD) + (size_t)nr*768 + h*DD + d] = (f16)W[r];
}

// ---------------- FUSED agg+GEMM: xout = relu(AGG(x,q)[tile 32] @ Wc.T + bias) ----------------
// Phase A: 8 waves aggregate 32 nodes into LDS (XOR-swizzled rows, stride 1536B).
// Phase B: MFMA from LDS-A + double-buffered global_load_lds B.
// global_load_lds dest = base + t*16 (HW pattern: wave-uniform base + lane*16).
// LDS = 48KB A + 2x16KB B = 80KB -> 2 blocks/CU (16 waves/CU).
__global__ __launch_bounds__(512) void fused_kernel(const f16* __restrict__ x,
                           const f16* __restrict__ qcsr,
                           const int* __restrict__ rowptr, const int2* __restrict__ sd_pair,
                           const f16* __restrict__ Wc, const float* __restrict__ bias,
                           f16* __restrict__ xout, int n) {
  __shared__ char lds[81920];
  const int t = threadIdx.x;
  const int l = t & 63;
  const int wave = t >> 6;               // 0..7
  const int tile = blockIdx.x * 32;

  // ================= phase A: aggregate, 4 nodes per wave =================
  for (int i = 0; i < 4; i++) {
    int nl = wave * 4 + i;               // node_local 0..31
    int node = tile + nl;
    float acc0[HH] = {0,0,0,0,0,0};
    float acc1[HH] = {0,0,0,0,0,0};
    if (node < n) {
      int p0 = rowptr[node], p1 = rowptr[node+1];
      int p = p0;
      for (; p + 4 <= p1; p += 4) {
        int s[4];
        #pragma unroll
        for (int u = 0; u < 4; u++) s[u] = sd_pair[p+u].x;
        f16x2 xv[4];
        #pragma unroll
        for (int u = 0; u < 4; u++) xv[u] = *(const f16x2*)&x[(size_t)s[u]*DD + 2*l];
        const f16x2* qp = (const f16x2*)(qcsr + (size_t)p*HH);
        f16x2 qv[12];
        #pragma unroll
        for (int u = 0; u < 12; u++) qv[u] = qp[u];
        #pragma unroll
        for (int u = 0; u < 4; u++) {
          float x0 = (float)xv[u][0], x1 = (float)xv[u][1];
          float qh[HH] = {(float)qv[u*3+0][0], (float)qv[u*3+0][1],
                          (float)qv[u*3+1][0], (float)qv[u*3+1][1],
                          (float)qv[u*3+2][0], (float)qv[u*3+2][1]};
          #pragma unroll
          for (int h = 0; h < HH; h++) {
            acc0[h] = fmaf(qh[h], x0, acc0[h]);
            acc1[h] = fmaf(qh[h], x1, acc1[h]);
          }
        }
      }
      for (; p < p1; p++) {
        int s = sd_pair[p].x;
        const f16x2* qp = (const f16x2*)(qcsr + (size_t)p*HH);
        f16x2 q01 = qp[0], q23 = qp[1], q45 = qp[2];
        f16x2 xv = *(const f16x2*)&x[(size_t)s*DD + 2*l];
        float x0 = (float)xv[0], x1 = (float)xv[1];
        float qh[HH] = {(float)q01[0], (float)q01[1], (float)q23[0],
                        (float)q23[1], (float)q45[0], (float)q45[1]};
        #pragma unroll
        for (int h = 0; h < HH; h++) {
          acc0[h] = fmaf(qh[h], x0, acc0[h]);
          acc1[h] = fmaf(qh[h], x1, acc1[h]);
        }
      }
    }
    // write agg row to LDS, swizzled: elem k = h*128 + {2l, 2l+1} -> byte (256h+4l)^((nl&7)<<4)
    char* Arow = lds + nl * 1536;
    int swz = (nl & 7) << 4;
    #pragma unroll
    for (int h = 0; h < HH; h++) {
      f16x2 o = {(f16)acc0[h], (f16)acc1[h]};
      *(f16x2*)(Arow + ((h*256 + 4*l) ^ swz)) = o;
    }
  }

  // ================= phase B: GEMM 32x128, K=768 =================
  // stage: thread t writes 16B at B_lds[t*16 + i*8192] = row r*128 + (t&7)*16,
  // r = (t>>3) + i*64; source col-byte inverse-swizzled.
  auto stageB = [&](int ks, int buf) {
    int k0 = ks * 64;
    char* Bd = lds + 49152 + buf * 16384 + t * 16;
    #pragma unroll
    for (int i = 0; i < 2; i++) {
      int r = (t >> 3) + i * 64;
      int cb = ((t & 7) * 16) ^ ((r & 7) << 4);      // inverse swizzle on source
      const f16* gb = Wc + (size_t)r * 768 + k0 + (cb >> 1);
      __builtin_amdgcn_global_load_lds(
          (const __attribute__((address_space(1))) void*)gb,
          (__attribute__((address_space(3))) void*)(Bd + i * 8192), 16, 0, 0);
    }
  };

  const int r16 = l & 15, kc = l >> 4;
  const int wM = wave >> 2, wN = wave & 3;           // 2 x 4 wave grid
  const int arow = wM * 16 + r16;
  const char* ArowB = lds + arow * 1536;
  const int axr = (arow & 7) << 4;

  f32x4 acc[2];
  acc[0] = (f32x4){0.f,0.f,0.f,0.f};
  acc[1] = (f32x4){0.f,0.f,0.f,0.f};

  stageB(0, 0);
  __syncthreads();                                   // also fences phase-A LDS writes

  for (int ks = 0; ks < 12; ks++) {
    int buf = ks & 1;
    if (ks < 11) stageB(ks + 1, buf ^ 1);
    const char* Bb = lds + 49152 + buf * 16384;
    #pragma unroll
    for (int kk = 0; kk < 2; kk++) {
      f16x8 a = *(const f16x8*)(ArowB + ((ks*128 + kk*64 + kc*16) ^ axr));
      #pragma unroll
      for (int nn = 0; nn < 2; nn++) {
        int bro = wN*32 + nn*16 + r16;
        f16x8 b = *(const f16x8*)(Bb + bro*128 + ((kk*64 + kc*16) ^ ((bro & 7) << 4)));
        acc[nn] = __builtin_amdgcn_mfma_f32_16x16x32_f16(a, b, acc[nn], 0, 0, 0);
      }
    }
    __syncthreads();
  }

  #pragma unroll
  for (int nn = 0; nn < 2; nn++) {
    int col = wN*32 + nn*16 + r16;
    float bv = bias[col];
    int rbase = tile + wM*16 + kc*4;
    #pragma unroll
    for (int rr = 0; rr < 4; rr++) {
      int gm = rbase + rr;
      if (gm < n) xout[(size_t)gm*DD + col] = (f16)fmaxf(acc[nn][rr] + bv, 0.f);
    }
  }
}

// ---------------- final: out = x @ w2.T + b2  [N,3] (x fp16) ----------------
__global__ void fin_kernel(const f16* __restrict__ x, const float* __restrict__ w2,
                           const float* __restrict__ b2, float* __restrict__ out, int n) {
  int node = blockIdx.x*4 + (threadIdx.x >> 6);
  int l = threadIdx.x & 63;
  if (node >= n) return;
  f16x2 v = *(const f16x2*)&x[(size_t)node*DD + 2*l];
  float vx = (float)v[0], vy = (float)v[1];
  float p[3];
  #pragma unroll
  for (int o = 0; o < 3; o++) {
    float2 w = *(const float2*)&w2[o*DD + 2*l];
    p[o] = vx*w.x + vy*w.y;
  }
  #pragma unroll
  for (int off = 32; off; off >>= 1) {
    #pragma unroll
    for (int o = 0; o < 3; o++) p[o] += __shfl_xor(p[o], off, 64);
  }
  if (l == 0) {
    #pragma unroll
    for (int o = 0; o < 3; o++) out[(size_t)node*3 + o] = p[o] + b2[o];
  }
}

extern "C" void kernel_launch(void* const* d_in, const int* in_sizes, int n_in,
                              void* d_out, int out_size, void* d_ws, size_t ws_size,
                              hipStream_t stream) {
  const float* pos = (const float*)d_in[0];
  const float* nrm = (const float*)d_in[1];
  const int*   ei  = (const int*)d_in[2];
  const float* w1  = (const float*)d_in[3];
  const float* b1  = (const float*)d_in[4];
  const float* w2  = (const float*)d_in[5];
  const float* b2  = (const float*)d_in[6];
  const float* Wg[4] = {(const float*)d_in[7],  (const float*)d_in[11],
                        (const float*)d_in[15], (const float*)d_in[19]};
  const float* uu[4] = {(const float*)d_in[8],  (const float*)d_in[12],
                        (const float*)d_in[16], (const float*)d_in[20]};
  const float* cc[4] = {(const float*)d_in[9],  (const float*)d_in[13],
                        (const float*)d_in[17], (const float*)d_in[21]};
  const float* bg[4] = {(const float*)d_in[10], (const float*)d_in[14],
                        (const float*)d_in[18], (const float*)d_in[22]};
  int n = in_sizes[0] / 3;
  int e = in_sizes[2] / 2;
  const int* src = ei;
  const int* dst = ei + e;

  char* p = (char*)d_ws;
  auto alloc = [&](size_t bytes) -> void* {
    void* r = (void*)p;
    p += (bytes + 255) & ~(size_t)255;
    return r;
  };
  f16*   xa     = (f16*)alloc((size_t)n*DD*2);
  f16*   xb     = (f16*)alloc((size_t)n*DD*2);
  f16*   qcsr   = (f16*)alloc((size_t)e*HH*2);
  f16*   wcb    = (f16*)alloc((size_t)4*HH*DD*DD*2);
  float* zbuf   = (float*)alloc((size_t)n*HH*4);
  float* invdeg = (float*)alloc((size_t)n*4);
  int*   cnt    = (int*)alloc((size_t)n*4);
  int*   rowptr = (int*)alloc((size_t)(n+1)*4);
  int*   fc     = (int*)alloc((size_t)n*4);
  int2*  sd_pair= (int2*)alloc((size_t)e*8);
  int*   bsum   = (int*)alloc(4096);

  hipMemsetAsync(cnt, 0, (size_t)n*4, stream);
  hipMemsetAsync(fc,  0, (size_t)n*4, stream);

  int eb = (e + 255)/256;
  int nb = (n + 255)/256;

  enc_kernel<<<n, 128, 0, stream>>>(pos, nrm, w1, b1, xa, n);
  hist_kernel<<<eb, 256, 0, stream>>>(dst, e, cnt);
  wc4_kernel<<<(4*HH*DD*DD + 255)/256, 256, 0, stream>>>(Wg[0], Wg[1], Wg[2], Wg[3], wcb);
  scan_blk_kernel<<<nb, 256, 0, stream>>>(cnt, rowptr, bsum, n);
  scan_top_kernel<<<1, 256, 0, stream>>>(bsum, nb);
  scan_add_kernel<<<nb, 256, 0, stream>>>(rowptr, bsum, cnt, invdeg, n, e);
  fill_kernel<<<eb, 256, 0, stream>>>(src, dst, e, rowptr, fc, sd_pair);

  f16* xin = xa;
  f16* xout = xb;
  int fb = (n + 31)/32;
  for (int l = 0; l < 4; l++) {
    z_kernel<<<(n+3)/4, 256, 0, stream>>>(xin, uu[l], zbuf, n);
    q_kernel<<<eb, 256, 0, stream>>>(sd_pair, zbuf, cc[l], invdeg, qcsr, e);
    fused_kernel<<<fb, 512, 0, stream>>>(xin, qcsr, rowptr, sd_pair,
                                         wcb + (size_t)l*HH*DD*DD, bg[l], xout, n);
    f16* t = xin; xin = xout; xout = t;
  }
  fin_kernel<<<(n+3)/4, 256, 0, stream>>>(xin, w2, b2, (float*)d_out, n);
}

// Round 15
// 661.921 us; speedup vs baseline: 1.0555x; 1.0555x over previous
//
#include <hip/hip_runtime.h>
#include <hip/hip_fp16.h>

#define DD 128
#define HH 6

typedef _Float16 f16;
typedef _Float16 f16x2 __attribute__((ext_vector_type(2)));
typedef _Float16 f16x8 __attribute__((ext_vector_type(8)));
typedef float f32x4 __attribute__((ext_vector_type(4)));

// ---------------- encoder: x = relu([pos,norm] @ w1.T + b1) -> fp16 ----------------
__global__ void enc_kernel(const float* __restrict__ pos, const float* __restrict__ nrm,
                           const float* __restrict__ w1, const float* __restrict__ b1,
                           f16* __restrict__ x, int n) {
  int i = blockIdx.x;
  int d = threadIdx.x;
  if (i >= n) return;
  float in[6];
  in[0] = pos[i*3+0]; in[1] = pos[i*3+1]; in[2] = pos[i*3+2];
  in[3] = nrm[i*3+0]; in[4] = nrm[i*3+1]; in[5] = nrm[i*3+2];
  const float* wr = w1 + d*6;
  float acc = b1[d];
  #pragma unroll
  for (int k = 0; k < 6; k++) acc = fmaf(in[k], wr[k], acc);
  x[(size_t)i*DD + d] = (f16)fmaxf(acc, 0.0f);
}

// ---------------- degree histogram ----------------
__global__ void hist_kernel(const int* __restrict__ dst, int e, int* __restrict__ cnt) {
  int i = blockIdx.x*blockDim.x + threadIdx.x;
  if (i < e) atomicAdd(&cnt[dst[i]], 1);
}

// ---------------- exclusive scan (3 kernels) ----------------
__global__ void scan_blk_kernel(const int* __restrict__ cnt, int* __restrict__ rowptr,
                                int* __restrict__ bsum, int n) {
  __shared__ int s[256];
  int tid = threadIdx.x;
  int i = blockIdx.x*256 + tid;
  int v = (i < n) ? cnt[i] : 0;
  s[tid] = v; __syncthreads();
  #pragma unroll
  for (int off = 1; off < 256; off <<= 1) {
    int t = (tid >= off) ? s[tid-off] : 0;
    __syncthreads();
    s[tid] += t;
    __syncthreads();
  }
  if (i < n) rowptr[i] = s[tid] - v;
  if (tid == 255) bsum[blockIdx.x] = s[255];
}

__global__ void scan_top_kernel(int* bsum, int nb) {
  __shared__ int s[256];
  int tid = threadIdx.x;
  int v = (tid < nb) ? bsum[tid] : 0;
  s[tid] = v; __syncthreads();
  #pragma unroll
  for (int off = 1; off < 256; off <<= 1) {
    int t = (tid >= off) ? s[tid-off] : 0;
    __syncthreads();
    s[tid] += t;
    __syncthreads();
  }
  if (tid < nb) bsum[tid] = s[tid] - v;
}

// rowptr finalize + invdeg fused
__global__ void scan_add_kernel(int* rowptr, const int* __restrict__ bsum,
                                const int* __restrict__ cnt, float* __restrict__ invdeg,
                                int n, int e) {
  int i = blockIdx.x*256 + threadIdx.x;
  if (i < n) {
    rowptr[i] += bsum[blockIdx.x];
    invdeg[i] = 1.0f / (float)max(cnt[i], 1);
  }
  if (i == 0) rowptr[n] = e;
}

// ---------------- CSR fill: sd_pair[p] = {src, dst}  (single 8B scatter/edge) ----------------
__global__ void fill_kernel(const int* __restrict__ src, const int* __restrict__ dst, int e,
                            const int* __restrict__ rowptr, int* __restrict__ fc,
                            int2* __restrict__ sd_pair) {
  int i = blockIdx.x*blockDim.x + threadIdx.x;
  if (i >= e) return;
  int dd = dst[i];
  int p = rowptr[dd] + atomicAdd(&fc[dd], 1);
  sd_pair[p] = make_int2(src[i], dd);
}

// ---------------- z = x @ u.T  [N,6]  (x fp16) ----------------
__global__ void z_kernel(const f16* __restrict__ x, const float* __restrict__ u,
                         float* __restrict__ z, int n) {
  int node = blockIdx.x*4 + (threadIdx.x >> 6);
  int l = threadIdx.x & 63;
  if (node >= n) return;
  f16x2 v = *(const f16x2*)&x[(size_t)node*DD + 2*l];
  float vx = (float)v[0], vy = (float)v[1];
  float p[HH];
  #pragma unroll
  for (int h = 0; h < HH; h++) {
    float2 uv = *(const float2*)&u[h*DD + 2*l];
    p[h] = vx*uv.x + vy*uv.y;
  }
  #pragma unroll
  for (int off = 32; off; off >>= 1) {
    #pragma unroll
    for (int h = 0; h < HH; h++) p[h] += __shfl_xor(p[h], off, 64);
  }
  if (l == 0) {
    #pragma unroll
    for (int h = 0; h < HH; h++) z[(size_t)node*HH + h] = p[h];
  }
}

// ---------------- per-slot softmax -> fp16 q sequential (deg-divide folded) ----------------
__global__ void q_kernel(const int2* __restrict__ sd_pair,
                         const float* __restrict__ z, const float* __restrict__ c,
                         const float* __restrict__ invdeg,
                         f16* __restrict__ qcsr, int e) {
  int i = blockIdx.x*blockDim.x + threadIdx.x;
  if (i >= e) return;
  int2 sd = sd_pair[i];
  int s = sd.x, dd = sd.y;
  float l[HH];
  float m = -1e30f;
  #pragma unroll
  for (int h = 0; h < HH; h++) {
    l[h] = z[(size_t)s*HH + h] - z[(size_t)dd*HH + h] + c[h];
    m = fmaxf(m, l[h]);
  }
  float sum = 0.f;
  #pragma unroll
  for (int h = 0; h < HH; h++) { l[h] = __expf(l[h] - m); sum += l[h]; }
  float r = invdeg[dd] / sum;
  size_t p = (size_t)i*HH;
  f16x2 o0 = {(f16)(l[0]*r), (f16)(l[1]*r)};
  f16x2 o1 = {(f16)(l[2]*r), (f16)(l[3]*r)};
  f16x2 o2 = {(f16)(l[4]*r), (f16)(l[5]*r)};
  *(f16x2*)&qcsr[p+0] = o0;
  *(f16x2*)&qcsr[p+2] = o1;
  *(f16x2*)&qcsr[p+4] = o2;
}

// ---------------- CSR aggregation: agg[i][h*128+d] = sum_p q[p][h]*x[src_p][d] ----------------
// unroll-4 edge loop (MLP), nontemporal agg stores (no RFO)
__global__ __launch_bounds__(256) void agg_kernel(const f16* __restrict__ x,
                           const f16* __restrict__ qcsr,
                           const int* __restrict__ rowptr, const int2* __restrict__ sd_pair,
                           f16* __restrict__ agg, int n) {
  int node = blockIdx.x*4 + (threadIdx.x >> 6);
  int t = threadIdx.x & 63;
  if (node >= n) return;
  float acc0[HH] = {0,0,0,0,0,0};
  float acc1[HH] = {0,0,0,0,0,0};
  int p0 = rowptr[node], p1 = rowptr[node+1];
  int p = p0;
  for (; p + 4 <= p1; p += 4) {
    int s[4];
    #pragma unroll
    for (int u = 0; u < 4; u++) s[u] = sd_pair[p+u].x;
    f16x2 xv[4];
    #pragma unroll
    for (int u = 0; u < 4; u++) xv[u] = *(const f16x2*)&x[(size_t)s[u]*DD + 2*t];
    const f16x2* qp = (const f16x2*)(qcsr + (size_t)p*HH);
    f16x2 qv[12];
    #pragma unroll
    for (int u = 0; u < 12; u++) qv[u] = qp[u];
    #pragma unroll
    for (int u = 0; u < 4; u++) {
      float x0 = (float)xv[u][0], x1 = (float)xv[u][1];
      float qh[HH] = {(float)qv[u*3+0][0], (float)qv[u*3+0][1],
                      (float)qv[u*3+1][0], (float)qv[u*3+1][1],
                      (float)qv[u*3+2][0], (float)qv[u*3+2][1]};
      #pragma unroll
      for (int h = 0; h < HH; h++) {
        acc0[h] = fmaf(qh[h], x0, acc0[h]);
        acc1[h] = fmaf(qh[h], x1, acc1[h]);
      }
    }
  }
  for (; p < p1; p++) {
    int s = sd_pair[p].x;
    const f16x2* qp = (const f16x2*)(qcsr + (size_t)p*HH);
    f16x2 q01 = qp[0], q23 = qp[1], q45 = qp[2];
    f16x2 xv = *(const f16x2*)&x[(size_t)s*DD + 2*t];
    float x0 = (float)xv[0], x1 = (float)xv[1];
    float qh[HH] = {(float)q01[0], (float)q01[1], (float)q23[0],
                    (float)q23[1], (float)q45[0], (float)q45[1]};
    #pragma unroll
    for (int h = 0; h < HH; h++) {
      acc0[h] = fmaf(qh[h], x0, acc0[h]);
      acc1[h] = fmaf(qh[h], x1, acc1[h]);
    }
  }
  #pragma unroll
  for (int h = 0; h < HH; h++) {
    f16x2 o = {(f16)acc0[h], (f16)acc1[h]};
    __builtin_nontemporal_store(__builtin_bit_cast(unsigned, o),
        (unsigned*)&agg[(size_t)node*768 + h*DD + 2*t]);
  }
}

// ---------------- W concat+convert, all 4 layers: Wc[l][nr][h*128+d] = (f16)W_l[h][nr][d] ----------------
__global__ void wc4_kernel(const float* __restrict__ W0, const float* __restrict__ W1,
                           const float* __restrict__ W2, const float* __restrict__ W3,
                           f16* __restrict__ Wc) {
  int id = blockIdx.x*256 + threadIdx.x;
  if (id >= 4*HH*DD*DD) return;
  int l = id / (HH*DD*DD);
  int r = id - l*(HH*DD*DD);
  const float* W = (l == 0) ? W0 : (l == 1) ? W1 : (l == 2) ? W2 : W3;
  int h = r >> 14, rem = r & 16383, nr = rem >> 7, d = rem & 127;
  Wc[(size_t)l*(HH*DD*DD) + (size_t)nr*768 + h*DD + d] = (f16)W[r];
}

// ---------------- MFMA GEMM: xout = relu(agg[n,768] @ Wc.T + bias) ----------------
// 64x128 tile, BK=64, double-buffered global_load_lds(16B), XOR-swizzled LDS.
// 48KB LDS -> 3 blocks/CU; 782 blocks all co-resident (hides barrier drain).
// 4 waves in 2x2 grid; wave = 32x64 via 2x4 16x16x32 MFMA frags.
__global__ __launch_bounds__(256) void gemm_kernel(const f16* __restrict__ A,
                                                   const f16* __restrict__ Wc,
                                                   const float* __restrict__ bias,
                                                   f16* __restrict__ xout, int n) {
  __shared__ char lds[49152];           // A: 2 x 8KB, B: 2 x 16KB
  const int t = threadIdx.x;
  const int l = t & 63;
  const int wave = t >> 6;
  const int wM = wave >> 1, wN = wave & 1;
  const int r16 = l & 15, kc = l >> 4;
  const int m0 = blockIdx.x * 64;

  auto stage = [&](int ks, int buf) {
    const int k0 = ks * 64;
    char* Ad = lds + buf * 8192 + t * 16;
    char* Bd = lds + 16384 + buf * 16384 + t * 16;
    #pragma unroll
    for (int i = 0; i < 2; i++) {       // A: 64 rows
      int r = (t >> 3) + i * 32;
      int cb = ((t & 7) * 16) ^ ((r & 7) << 4);
      const f16* ga = A + (size_t)(m0 + r) * 768 + k0 + (cb >> 1);
      __builtin_amdgcn_global_load_lds(
          (const __attribute__((address_space(1))) void*)ga,
          (__attribute__((address_space(3))) void*)(Ad + i * 4096), 16, 0, 0);
    }
    #pragma unroll
    for (int i = 0; i < 4; i++) {       // B: 128 rows
      int r = (t >> 3) + i * 32;
      int cb = ((t & 7) * 16) ^ ((r & 7) << 4);
      const f16* gb = Wc + (size_t)r * 768 + k0 + (cb >> 1);
      __builtin_amdgcn_global_load_lds(
          (const __attribute__((address_space(1))) void*)gb,
          (__attribute__((address_space(3))) void*)(Bd + i * 4096), 16, 0, 0);
    }
  };

  f32x4 acc[2][4];
  #pragma unroll
  for (int m = 0; m < 2; m++)
    #pragma unroll
    for (int nn = 0; nn < 4; nn++) acc[m][nn] = (f32x4){0.f, 0.f, 0.f, 0.f};

  stage(0, 0);
  __syncthreads();

  for (int ks = 0; ks < 12; ks++) {
    int buf = ks & 1;
    if (ks < 11) stage(ks + 1, buf ^ 1);
    const char* Ab = lds + buf * 8192;
    const char* Bb = lds + 16384 + buf * 16384;
    #pragma unroll
    for (int kk = 0; kk < 2; kk++) {
      int kb = kk * 64 + kc * 16;
      f16x8 a[2], b[4];
      #pragma unroll
      for (int m = 0; m < 2; m++) {
        int ar = wM*32 + m*16 + r16;
        a[m] = *(const f16x8*)(Ab + ar*128 + (kb ^ ((ar & 7) << 4)));
      }
      #pragma unroll
      for (int nn = 0; nn < 4; nn++) {
        int bro = wN*64 + nn*16 + r16;
        b[nn] = *(const f16x8*)(Bb + bro*128 + (kb ^ ((bro & 7) << 4)));
      }
      #pragma unroll
      for (int m = 0; m < 2; m++)
        #pragma unroll
        for (int nn = 0; nn < 4; nn++)
          acc[m][nn] = __builtin_amdgcn_mfma_f32_16x16x32_f16(a[m], b[nn], acc[m][nn], 0, 0, 0);
    }
    __syncthreads();
  }

  #pragma unroll
  for (int nn = 0; nn < 4; nn++) {
    int col = wN*64 + nn*16 + r16;
    float bv = bias[col];
    #pragma unroll
    for (int m = 0; m < 2; m++) {
      int rbase = m0 + wM*32 + m*16 + kc*4;
      #pragma unroll
      for (int rr = 0; rr < 4; rr++) {
        int gm = rbase + rr;
        if (gm < n) xout[(size_t)gm*DD + col] = (f16)fmaxf(acc[m][nn][rr] + bv, 0.f);
      }
    }
  }
}

// ---------------- final: out = x @ w2.T + b2  [N,3] (x fp16) ----------------
__global__ void fin_kernel(const f16* __restrict__ x, const float* __restrict__ w2,
                           const float* __restrict__ b2, float* __restrict__ out, int n) {
  int node = blockIdx.x*4 + (threadIdx.x >> 6);
  int l = threadIdx.x & 63;
  if (node >= n) return;
  f16x2 v = *(const f16x2*)&x[(size_t)node*DD + 2*l];
  float vx = (float)v[0], vy = (float)v[1];
  float p[3];
  #pragma unroll
  for (int o = 0; o < 3; o++) {
    float2 w = *(const float2*)&w2[o*DD + 2*l];
    p[o] = vx*w.x + vy*w.y;
  }
  #pragma unroll
  for (int off = 32; off; off >>= 1) {
    #pragma unroll
    for (int o = 0; o < 3; o++) p[o] += __shfl_xor(p[o], off, 64);
  }
  if (l == 0) {
    #pragma unroll
    for (int o = 0; o < 3; o++) out[(size_t)node*3 + o] = p[o] + b2[o];
  }
}

extern "C" void kernel_launch(void* const* d_in, const int* in_sizes, int n_in,
                              void* d_out, int out_size, void* d_ws, size_t ws_size,
                              hipStream_t stream) {
  const float* pos = (const float*)d_in[0];
  const float* nrm = (const float*)d_in[1];
  const int*   ei  = (const int*)d_in[2];
  const float* w1  = (const float*)d_in[3];
  const float* b1  = (const float*)d_in[4];
  const float* w2  = (const float*)d_in[5];
  const float* b2  = (const float*)d_in[6];
  const float* Wg[4] = {(const float*)d_in[7],  (const float*)d_in[11],
                        (const float*)d_in[15], (const float*)d_in[19]};
  const float* uu[4] = {(const float*)d_in[8],  (const float*)d_in[12],
                        (const float*)d_in[16], (const float*)d_in[20]};
  const float* cc[4] = {(const float*)d_in[9],  (const float*)d_in[13],
                        (const float*)d_in[17], (const float*)d_in[21]};
  const float* bg[4] = {(const float*)d_in[10], (const float*)d_in[14],
                        (const float*)d_in[18], (const float*)d_in[22]};
  int n = in_sizes[0] / 3;
  int e = in_sizes[2] / 2;
  const int* src = ei;
  const int* dst = ei + e;

  char* p = (char*)d_ws;
  auto alloc = [&](size_t bytes) -> void* {
    void* r = (void*)p;
    p += (bytes + 255) & ~(size_t)255;
    return r;
  };
  f16*   xa     = (f16*)alloc((size_t)n*DD*2);
  f16*   xb     = (f16*)alloc((size_t)n*DD*2);
  f16*   agg    = (f16*)alloc((size_t)n*768*2 + 131072);  // slack for tail-tile OOB reads
  f16*   qcsr   = (f16*)alloc((size_t)e*HH*2);
  f16*   wcb    = (f16*)alloc((size_t)4*HH*DD*DD*2);
  float* zbuf   = (float*)alloc((size_t)n*HH*4);
  float* invdeg = (float*)alloc((size_t)n*4);
  int*   cnt    = (int*)alloc((size_t)n*4);
  int*   rowptr = (int*)alloc((size_t)(n+1)*4);
  int*   fc     = (int*)alloc((size_t)n*4);
  int2*  sd_pair= (int2*)alloc((size_t)e*8);
  int*   bsum   = (int*)alloc(4096);

  hipMemsetAsync(cnt, 0, (size_t)n*4, stream);
  hipMemsetAsync(fc,  0, (size_t)n*4, stream);

  int eb = (e + 255)/256;
  int nb = (n + 255)/256;

  enc_kernel<<<n, 128, 0, stream>>>(pos, nrm, w1, b1, xa, n);
  hist_kernel<<<eb, 256, 0, stream>>>(dst, e, cnt);
  wc4_kernel<<<(4*HH*DD*DD + 255)/256, 256, 0, stream>>>(Wg[0], Wg[1], Wg[2], Wg[3], wcb);
  scan_blk_kernel<<<nb, 256, 0, stream>>>(cnt, rowptr, bsum, n);
  scan_top_kernel<<<1, 256, 0, stream>>>(bsum, nb);
  scan_add_kernel<<<nb, 256, 0, stream>>>(rowptr, bsum, cnt, invdeg, n, e);
  fill_kernel<<<eb, 256, 0, stream>>>(src, dst, e, rowptr, fc, sd_pair);

  f16* xin = xa;
  f16* xout = xb;
  for (int l = 0; l < 4; l++) {
    z_kernel<<<(n+3)/4, 256, 0, stream>>>(xin, uu[l], zbuf, n);
    q_kernel<<<eb, 256, 0, stream>>>(sd_pair, zbuf, cc[l], invdeg, qcsr, e);
    agg_kernel<<<(n+3)/4, 256, 0, stream>>>(xin, qcsr, rowptr, sd_pair, agg, n);
    gemm_kernel<<<(n+63)/64, 256, 0, stream>>>(agg, wcb + (size_t)l*HH*DD*DD, bg[l], xout, n);
    f16* t = xin; xin = xout; xout = t;
  }
  fin_kernel<<<(n+3)/4, 256, 0, stream>>>(xin, w2, b2, (float*)d_out, n);
}